// Round 2
// baseline (261.559 us; speedup 1.0000x reference)
//
#include <hip/hip_runtime.h>
#include <stdint.h>

typedef float f32x16 __attribute__((ext_vector_type(16)));
typedef short bf16x8 __attribute__((ext_vector_type(8)));
typedef uint32_t u32;

#define T_LEN 8192
#define E_DIM 64
#define WSZ   128
#define NWIN  64
#define NBH   32
#define SCALE 0.125f

union Frag { u32 w[4]; bf16x8 v; };

__device__ __forceinline__ u32 pkbf(float a, float b) {
    u32 r;
    asm("v_cvt_pk_bf16_f32 %0, %1, %2" : "=v"(r) : "v"(a), "v"(b));
    return r;
}

// K tile: bf16 [256 keys][64 e], row = 128B, XOR-swizzled (bijective; same fn
// for read and write) to spread the 128B-stride column reads across banks.
__device__ __forceinline__ u32 kaddr(u32 key, u32 bir) {
    return (key * 128u + bir) ^ ((key & 15u) << 4);
}

// One 32-key S block: pack P->bf16, lane^32 exchange, PV with V read directly
// from global (rows are L1/L2-hot). ksbase = key_block/16 (global 0..15).
__device__ __forceinline__ void pv_half(const f32x16& a, int ksbase, int h, int ql,
                                        long krow0, const float* __restrict__ vg,
                                        f32x16& o0, f32x16& o1) {
    u32 W[8];
#pragma unroll
    for (int j = 0; j < 8; ++j) W[j] = pkbf(a[2 * j], a[2 * j + 1]);
#pragma unroll
    for (int hi = 0; hi < 2; ++hi) {
        const u32 w0 = W[4 * hi + 0], w1 = W[4 * hi + 1];
        const u32 w2 = W[4 * hi + 2], w3 = W[4 * hi + 3];
        const u32 y0 = (u32)__shfl_xor((int)w0, 32);
        const u32 y1 = (u32)__shfl_xor((int)w1, 32);
        const u32 y2 = (u32)__shfl_xor((int)w2, 32);
        const u32 y3 = (u32)__shfl_xor((int)w3, 32);
        Frag au;
        // dest h=0: elems0-3 = own regs, elems4-7 = partner low regs
        // dest h=1: elems0-3 = partner high regs, elems4-7 = own high regs
        au.w[0] = h ? y2 : w0;
        au.w[1] = h ? y3 : w1;
        au.w[2] = h ? w2 : y0;
        au.w[3] = h ? w3 : y1;
        const int ks = ksbase + hi;
        // B-frag: keys 16ks+8h .. +7 at cols ql (o0) and ql+32 (o1)
        const long vr = (krow0 + (long)(16 * ks + 8 * h)) * E_DIM + ql;
        float v0[8], v1[8];
#pragma unroll
        for (int j = 0; j < 8; ++j) {
            v0[j] = vg[vr + (long)j * E_DIM];
            v1[j] = vg[vr + (long)j * E_DIM + 32];
        }
        Frag b0, b1;
#pragma unroll
        for (int j = 0; j < 4; ++j) {
            b0.w[j] = pkbf(v0[2 * j], v0[2 * j + 1]);
            b1.w[j] = pkbf(v1[2 * j], v1[2 * j + 1]);
        }
        o0 = __builtin_amdgcn_mfma_f32_32x32x16_bf16(au.v, b0.v, o0, 0, 0, 0);
        o1 = __builtin_amdgcn_mfma_f32_32x32x16_bf16(au.v, b1.v, o1, 0, 0, 0);
    }
}

__global__ __launch_bounds__(256, 3)
void lattn_kernel(const float* __restrict__ qg, const float* __restrict__ kg,
                  const float* __restrict__ vg, float* __restrict__ outg) {
    __shared__ __align__(16) char lds[32768];

    const int tid  = threadIdx.x;
    const int lane = tid & 63;
    const int wid  = tid >> 6;   // wave 0..3, owns queries [wid*32, wid*32+32)
    const int h    = lane >> 5;
    const int ql   = lane & 31;

    // XCD-contiguous window mapping
    const int bid = blockIdx.x;
    const int swz = ((bid & 7) << 8) | (bid >> 3);
    const int bh  = swz >> 6;
    const int w   = swz & 63;

    const size_t qrow0 = (size_t)bh * T_LEN + (size_t)w * WSZ;
    const long   krow0 = (long)bh * T_LEN + (long)(w - 1) * WSZ; // row of key 0

    // ---- Q fragments (B operand of S^T = K*Q^T), pre-scaled by 1/sqrt(e) ----
    Frag qf[4];
    {
        const float* qp = qg + (qrow0 + (size_t)(wid * 32 + ql)) * E_DIM;
#pragma unroll
        for (int ks = 0; ks < 4; ++ks) {
            float4 a = *(const float4*)(qp + ks * 16 + h * 8);
            float4 b = *(const float4*)(qp + ks * 16 + h * 8 + 4);
            qf[ks].w[0] = pkbf(a.x * SCALE, a.y * SCALE);
            qf[ks].w[1] = pkbf(a.z * SCALE, a.w * SCALE);
            qf[ks].w[2] = pkbf(b.x * SCALE, b.y * SCALE);
            qf[ks].w[3] = pkbf(b.z * SCALE, b.w * SCALE);
        }
    }

    // ---- stage K only (256 keys x 64 e, bf16). w==0: rows<128 never read. ----
#pragma unroll
    for (int i = 0; i < 16; ++i) {
        const int f   = i * 256 + tid;
        const int row = f >> 4;
        const int c   = f & 15;
        if (w > 0 || row >= 128) {
            const float4 kv = *(const float4*)(kg + (size_t)(krow0 + row) * E_DIM + c * 4);
            *(uint2*)(lds + kaddr((u32)row, (u32)c * 8u)) =
                make_uint2(pkbf(kv.x, kv.y), pkbf(kv.z, kv.w));
        }
    }
    __syncthreads();

    const int qpos = wid * 32 + ql;
    f32x16 o0, o1;
#pragma unroll
    for (int r = 0; r < 16; ++r) { o0[r] = 0.f; o1[r] = 0.f; }
    float den = 0.f;

    // key blocks of 64; w==0 skips the (absent) previous window
    const int qp0 = (w == 0) ? 2 : 0;
    for (int qp = qp0; qp < 4; ++qp) {
#pragma unroll
        for (int kf2 = 0; kf2 < 2; ++kf2) {
            // ---- S^T = K * Q^T for 32 keys ----
            f32x16 a;
#pragma unroll
            for (int r = 0; r < 16; ++r) a[r] = 0.f;
#pragma unroll
            for (int ks = 0; ks < 4; ++ks) {
                const bf16x8 kf = *(const bf16x8*)(lds +
                    kaddr((u32)(64 * qp + 32 * kf2 + ql), (u32)(32 * ks + 16 * h)));
                a = __builtin_amdgcn_mfma_f32_32x32x16_bf16(kf, qf[ks].v, a, 0, 0, 0);
            }
            // ---- mask + exp (no max subtract; |S| small, f32-safe) ----
            const int kb = 64 * qp + 32 * kf2 + 4 * h - 128; // key pos rel. window
#pragma unroll
            for (int r = 0; r < 16; ++r) {
                const int kr = kb + (r & 3) + 8 * (r >> 2);
                float p = __expf(a[r]);
                p = (kr <= qpos) ? p : 0.f;
                a[r] = p;
                den += p;
            }
            // ---- O += P * V ----
            pv_half(a, 4 * qp + 2 * kf2, h, ql, krow0, vg, o0, o1);
        }
    }

    den += __shfl_xor(den, 32);
    const float invd = 1.f / den;

    // ---- normalize + store (row of D = query, col = d) ----
    float* ob = outg + (qrow0 + (size_t)(wid * 32)) * E_DIM;
#pragma unroll
    for (int r = 0; r < 16; ++r) {
        const int rowq = (r & 3) + 8 * (r >> 2) + 4 * h;
        const float dn = __shfl(invd, rowq);
        ob[(size_t)rowq * E_DIM + ql]      = o0[r] * dn;
        ob[(size_t)rowq * E_DIM + 32 + ql] = o1[r] * dn;
    }
}

extern "C" void kernel_launch(void* const* d_in, const int* in_sizes, int n_in,
                              void* d_out, int out_size, void* d_ws, size_t ws_size,
                              hipStream_t stream) {
    const float* q = (const float*)d_in[0];
    const float* k = (const float*)d_in[1];
    const float* v = (const float*)d_in[2];
    float* out = (float*)d_out;
    lattn_kernel<<<dim3(NBH * NWIN), dim3(256), 0, stream>>>(q, k, v, out);
}